// Round 9
// baseline (8963.541 us; speedup 1.0000x reference)
//
#include <hip/hip_runtime.h>
#include <math.h>

// NeuralODE: sequential RK4 orbit propagation, J2-J5 gravity + tiny MLP.
// Single wave, latency-bound (stalls ~2.6:1 over issue). R9 = R8 +
//  (1) COMBINED HANDOFF: pre_{s+1} needs only dot(wc,s) -- computed from the
//      two uniform VGPRs {s0,s1} produced by mov+permlane32_swap (orientation
//      probed once at init; cA/cU weight pairs pre-selected). No readlanes,
//      no SGPR hazards on the critical path; s0/s1 recovered off-chain by
//      cndmask for the acceleration bookkeeping (>=1 stage of slack).
//  (2) L3 reduce+perm16+perm32 merged into ONE asm block (fewer s_nops).
// Lane map (R6): o = lid+16*bit4; ibase = 16*bit5; nin = lid+ibase.
// r01 rows: row0(o<16,x) row1(o>=16,x) row2(o<16,y) row3(o>=16,y).

namespace {
constexpr double dMU = 398600.4418;
constexpr double dRE = 6378.137;
constexpr double dJ2 = 0.00108262668;
constexpr double dJ3 = -2.53265648e-06;
constexpr double dJ4 = -1.61962159e-06;
constexpr double dJ5 = -2.27296082e-07;

constexpr float MU_F = (float)dMU;
constexpr float C2_F = (float)(-1.5 * dJ2 * dMU * dRE * dRE);
constexpr float C3_F = (float)(-2.5 * dJ3 * dMU * dRE * dRE * dRE);
constexpr float C4_F = (float)(15.0 / 8.0 * dJ4 * dMU * dRE * dRE * dRE * dRE);
constexpr float C5_F = (float)(3.0 / 8.0 * dJ5 * dMU * dRE * dRE * dRE * dRE * dRE);
constexpr float D5_F = (float)(-(15.0 / 8.0) * dJ5 * dMU * dRE * dRE * dRE * dRE * dRE);
constexpr float IRREF = (float)(1.0 / 7000.0);
constexpr float IVREF = (float)(1.0 / 7.5);
constexpr float AREF  = (float)(7.5 * 7.5 / 7000.0);
constexpr float L2E2  = 2.8853900817779268f;  // 2*log2(e)
} // namespace

typedef float f2 __attribute__((ext_vector_type(2)));
__device__ __forceinline__ f2 f2s(float s) { return (f2){s, s}; }
__device__ __forceinline__ f2 fma2(f2 a, f2 b, f2 c) {
    return __builtin_elementwise_fma(a, b, c);
}

template <int CTRL>
__device__ __forceinline__ int roti(int x) {
    return __builtin_amdgcn_update_dpp(0, x, CTRL, 0xf, 0xf, true);
}
// a+b = x[l] + x[l^32]  (verified R3 primitive; orientation-proof sum)
__device__ __forceinline__ float swap32sum(float x) {
    int a = __float_as_int(x), b = __float_as_int(x);
    asm("s_nop 0\n\tv_permlane32_swap_b32 %0, %1\n\ts_nop 0"
        : "+v"(a), "+v"(b));
    return __int_as_float(a) + __int_as_float(b);
}

struct G3 { f2 xy; float z; };

__global__ void __launch_bounds__(64, 1)
node_kernel(const float* __restrict__ state0,
            const float* __restrict__ W1, const float* __restrict__ b1,
            const float* __restrict__ W2, const float* __restrict__ b2,
            const float* __restrict__ W3, const float* __restrict__ b3,
            const float* __restrict__ plog_scale,
            const int*  __restrict__ pdt,
            float* __restrict__ out, int M)
{
    const int tid  = (int)threadIdx.x;
    const int lid  = tid & 15;
    const int o    = lid + (((tid >> 4) & 1) << 4);  // output neuron
    const int ibase = ((tid >> 5) & 1) << 4;          // input half base
    const int nin  = lid + ibase;                     // input neuron (L1)

    // dt arrives as a 1-element array; sniff int32 vs float32 bit pattern.
    int db = *pdt;
    float dtf = (db >= 1 && db <= 1000000) ? (float)db : __int_as_float(db);
    const float hd   = 0.5f * dtf;
    const float dt6  = dtf * (1.0f / 6.0f);
    const float hd2  = hd * hd;
    const float dthd = dtf * hd;
    const float dt26 = dtf * dtf * (1.0f / 6.0f);

    const float scale =
        __builtin_amdgcn_exp2f(plog_scale[0] * 1.4426950408889634f) * AREF;

    // ---- permlane32_swap orientation probe (R7-verified pattern): after
    // {mov A,x; swap A,x} both regs are uniform; cnd tells which is which. ----
    float pp = (tid & 32) ? 2.0f : 1.0f;
    int pa;
    int pb = __float_as_int(pp);
    asm("v_mov_b32 %0, %1\n\t"
        "s_nop 0\n\t"
        "v_permlane32_swap_b32 %0, %1\n\t"
        "s_nop 0"
        : "=&v"(pa), "+v"(pb));
    const bool cnd = (__int_as_float(pa) - __int_as_float(pb)) < 0.0f;
    // cnd==true  -> A-reg holds the LOW-half-origin value (s0), u01 holds s1.
    // cnd==false -> A-reg holds s1, u01 holds s0.

    // W3 column sums (tanh-fold constants)
    float Cx = 0.0f, Cy = 0.0f, Cz = 0.0f;
    for (int i = 0; i < 32; ++i) {
        Cx += W3[i]; Cy += W3[32 + i]; Cz += W3[64 + i];
    }
    // gravity bias: scale*(b3 + C)
    const f2   sbxy = (f2){scale * (b3[0] + Cx), scale * (b3[1] + Cy)};
    const float sbz = scale * (b3[2] + Cz);

    // ---- per-lane weights (pre-scaled by 2*log2e where they feed a tanh) ----
    const float w1p0 = W1[nin * 6 + 0] * (L2E2 * IRREF);
    const float w1p1 = W1[nin * 6 + 1] * (L2E2 * IRREF);
    const float w1p2 = W1[nin * 6 + 2] * (L2E2 * IRREF);
    const float w1v0 = W1[nin * 6 + 3] * (L2E2 * IVREF);
    const float w1v1 = W1[nin * 6 + 4] * (L2E2 * IVREF);
    const float w1v2 = W1[nin * 6 + 5] * (L2E2 * IVREF);
    const float b1r  = b1[nin] * L2E2;

    // self-calibrated DPP rotation source map (within-row lane index)
    int ns1  = roti<0x121>(lid), ns2  = roti<0x122>(lid), ns3  = roti<0x123>(lid);
    int ns4  = roti<0x124>(lid), ns5  = roti<0x125>(lid), ns6  = roti<0x126>(lid);
    int ns7  = roti<0x127>(lid), ns8  = roti<0x128>(lid), ns9  = roti<0x129>(lid);
    int ns10 = roti<0x12A>(lid), ns11 = roti<0x12B>(lid), ns12 = roti<0x12C>(lid);
    int ns13 = roti<0x12D>(lid), ns14 = roti<0x12E>(lid), ns15 = roti<0x12F>(lid);
    const float* W2r = W2 + o * 32 + ibase;
    const float NW = -2.0f * L2E2;   // negated-doubled (tanh fma absorbed)
    float w2n[16];
    w2n[0]  = W2r[lid]  * NW;
    w2n[1]  = W2r[ns1]  * NW;  w2n[2]  = W2r[ns2]  * NW;
    w2n[3]  = W2r[ns3]  * NW;  w2n[4]  = W2r[ns4]  * NW;
    w2n[5]  = W2r[ns5]  * NW;  w2n[6]  = W2r[ns6]  * NW;
    w2n[7]  = W2r[ns7]  * NW;  w2n[8]  = W2r[ns8]  * NW;
    w2n[9]  = W2r[ns9]  * NW;  w2n[10] = W2r[ns10] * NW;
    w2n[11] = W2r[ns11] * NW;  w2n[12] = W2r[ns12] * NW;
    w2n[13] = W2r[ns13] * NW;  w2n[14] = W2r[ns14] * NW;
    w2n[15] = W2r[ns15] * NW;
    // b2h: 0.5*L2E2*(b2[o] + full W2 row sum); swap32 doubles it back.
    float rowsum = 0.0f;
    for (int k = 0; k < 32; ++k) rowsum += W2[o * 32 + k];
    const float b2h = (b2[o] + rowsum) * (0.5f * L2E2);
    // L3 negated-doubled weights (x on ibase=0 half, y on ibase=16 half; z all)
    const float w3xyn = -2.0f * ((ibase == 0) ? W3[o] : W3[32 + o]);
    const float w3zn  = -2.0f * W3[64 + o];

    // chain-out weights (scale premultiplied); cA multiplies the A-reg,
    // cU multiplies the u01-reg (probe-resolved s0/s1 assignment).
    const float wcH0 = (scale * hd)  * w1v0, wcH1 = (scale * hd)  * w1v1,
                wcH2 = (scale * hd)  * w1v2;
    const float wcD0 = (scale * dtf) * w1v0, wcD1 = (scale * dtf) * w1v1,
                wcD2 = (scale * dtf) * w1v2;
    const float wc60 = (scale * dt6) * w1v0, wc61 = (scale * dt6) * w1v1,
                wc62 = (scale * dt6) * w1v2;
    const float cAH = cnd ? wcH0 : wcH1, cUH = cnd ? wcH1 : wcH0;
    const float cAD = cnd ? wcD0 : wcD1, cUD = cnd ? wcD1 : wcD0;
    const float cA6 = cnd ? wc60 : wc61, cU6 = cnd ? wc61 : wc60;
    // handoff constant folds: CH/CD/C6 = dt-weight * scale * (w1v . C)
    const float dCv = scale * (w1v0 * Cx + w1v1 * Cy + w1v2 * Cz);
    const float CH = hd * dCv, CD = dtf * dCv, C6 = dt6 * dCv;
    const float b1r6 = b1r + C6;

    auto dotP = [&](f2 xy, float z) {
        return fmaf(w1p2, z, fmaf(w1p1, xy.y, w1p0 * xy.x));
    };
    auto dotV = [&](f2 xy, float z) {
        return fmaf(w1v2, z, fmaf(w1v1, xy.y, w1v0 * xy.x));
    };

    // gravity with scale*(b3+C) folded in: returns g + sb'.
    auto gravity = [&](f2 pxy, float pz) -> G3 {
        float zz = pz * pz;
        float r2 = fmaf(pxy.x, pxy.x, fmaf(pxy.y, pxy.y, zz));
        float ir = __builtin_amdgcn_rsqf(r2);
        float ir2 = ir * ir, ir3 = ir2 * ir;
        float s  = zz * ir2;
        float s2 = s * s;
        f2 qp  = fma2(f2s(-5.0f), f2s(s), (f2){1.0f, 3.0f});
        f2 p4p = fma2(f2s(21.0f), f2s(s2),
                      fma2((f2){-14.0f, -70.0f / 3.0f}, f2s(s), (f2){1.0f, 5.0f}));
        f2 p5p = fma2(f2s(231.0f), f2s(s2),
                      fma2((f2){-210.0f, -315.0f}, f2s(s), (f2){35.0f, 105.0f}));
        f2 t3p = fma2(f2s(-7.0f), f2s(s), (f2){3.0f, 6.0f});
        float t3  = pz * t3p.x;
        float p3z = fmaf(s, t3p.y, -0.6f);
        float t5  = pz * p5p.x;
        f2 inner = (f2){fmaf(C3_F, t3, C4_F * p4p.x), C4_F * p4p.y};
        f2 H = fma2(f2s(ir2), (f2){C5_F * t5, 0.0f}, inner);
        H = fma2(f2s(ir2), H, f2s(C2_F) * qp);
        H = fma2(f2s(ir2), H, f2s(-MU_F));
        float Gxy = ir3 * H.x;
        float ir5 = ir3 * ir2;
        float w = fmaf(C5_F, s * p5p.y, D5_F);
        w = fmaf(ir2, w, C3_F * p3z);
        G3 g;
        g.xy = fma2(pxy, f2s(Gxy), sbxy);
        g.z  = fmaf(pz * ir3, H.y, fmaf(ir5, w, sbz));
        return g;
    };

    // MLP chain + combined handoff. Returns pre_{s+1} = PPfull + dot(wc,s).
    // s0/s1 (accel bookkeeping, off-chain) via cndmask; s2 uniform VGPR.
    auto mlpchain = [&](float pre, float PPfull, float cA_, float cU_,
                        float cZ_, float& s0, float& s1, float& s2) -> float {
        float e1  = __builtin_amdgcn_exp2f(pre);
        float rc1 = __builtin_amdgcn_rcpf(e1 + 1.0f);   // tanh = 1-2rc (folded)
        float a0 = fmaf(rc1, w2n[0], b2h);
        float a1, a2, a3;
        // 15 DPP-fused MACs; s_nop 1 covers VALU-write(rc1) -> DPP-read hazard.
        asm("s_nop 1\n\t"
            "v_mul_f32_dpp %1, %4, %5 row_ror:1 row_mask:0xf bank_mask:0xf\n\t"
            "v_mul_f32_dpp %2, %4, %6 row_ror:2 row_mask:0xf bank_mask:0xf\n\t"
            "v_mul_f32_dpp %3, %4, %7 row_ror:3 row_mask:0xf bank_mask:0xf\n\t"
            "v_fmac_f32_dpp %0, %4, %8 row_ror:4 row_mask:0xf bank_mask:0xf\n\t"
            "v_fmac_f32_dpp %1, %4, %9 row_ror:5 row_mask:0xf bank_mask:0xf\n\t"
            "v_fmac_f32_dpp %2, %4, %10 row_ror:6 row_mask:0xf bank_mask:0xf\n\t"
            "v_fmac_f32_dpp %3, %4, %11 row_ror:7 row_mask:0xf bank_mask:0xf\n\t"
            "v_fmac_f32_dpp %0, %4, %12 row_ror:8 row_mask:0xf bank_mask:0xf\n\t"
            "v_fmac_f32_dpp %1, %4, %13 row_ror:9 row_mask:0xf bank_mask:0xf\n\t"
            "v_fmac_f32_dpp %2, %4, %14 row_ror:10 row_mask:0xf bank_mask:0xf\n\t"
            "v_fmac_f32_dpp %3, %4, %15 row_ror:11 row_mask:0xf bank_mask:0xf\n\t"
            "v_fmac_f32_dpp %0, %4, %16 row_ror:12 row_mask:0xf bank_mask:0xf\n\t"
            "v_fmac_f32_dpp %1, %4, %17 row_ror:13 row_mask:0xf bank_mask:0xf\n\t"
            "v_fmac_f32_dpp %2, %4, %18 row_ror:14 row_mask:0xf bank_mask:0xf\n\t"
            "v_fmac_f32_dpp %3, %4, %19 row_ror:15 row_mask:0xf bank_mask:0xf"
            : "+v"(a0), "=&v"(a1), "=&v"(a2), "=&v"(a3)
            : "v"(rc1),
              "v"(w2n[1]), "v"(w2n[2]), "v"(w2n[3]), "v"(w2n[4]),
              "v"(w2n[5]), "v"(w2n[6]), "v"(w2n[7]), "v"(w2n[8]),
              "v"(w2n[9]), "v"(w2n[10]), "v"(w2n[11]), "v"(w2n[12]),
              "v"(w2n[13]), "v"(w2n[14]), "v"(w2n[15]));
        float accA = (a0 + a2) + (a1 + a3);
        float pre2 = swap32sum(accA);        // + other input half
        float e2  = __builtin_amdgcn_exp2f(pre2);
        float rc2 = __builtin_amdgcn_rcpf(e2 + 1.0f);
        float r01 = w3xyn * rc2;             // x rows0,1 ; y rows2,3
        float r2v = w3zn  * rc2;             // z halves within each 32-half
        float u01, s2v, A, tA, tB;
        // ONE merged block: rowsums -> perm16 self-sums -> u01/s2 adds ->
        // perm32 on u01 (A = partner value; both u01 and A end up uniform).
        asm("s_nop 1\n\t"
            "v_add_f32_dpp %0, %0, %0 row_ror:1 row_mask:0xf bank_mask:0xf\n\t"
            "v_add_f32_dpp %1, %1, %1 row_ror:1 row_mask:0xf bank_mask:0xf\n\t"
            "v_add_f32_dpp %0, %0, %0 row_ror:2 row_mask:0xf bank_mask:0xf\n\t"
            "v_add_f32_dpp %1, %1, %1 row_ror:2 row_mask:0xf bank_mask:0xf\n\t"
            "v_add_f32_dpp %0, %0, %0 row_ror:4 row_mask:0xf bank_mask:0xf\n\t"
            "v_add_f32_dpp %1, %1, %1 row_ror:4 row_mask:0xf bank_mask:0xf\n\t"
            "v_add_f32_dpp %0, %0, %0 row_ror:8 row_mask:0xf bank_mask:0xf\n\t"
            "v_add_f32_dpp %1, %1, %1 row_ror:8 row_mask:0xf bank_mask:0xf\n\t"
            "v_mov_b32 %5, %0\n\t"
            "v_mov_b32 %6, %1\n\t"
            "s_nop 0\n\t"
            "v_permlane16_swap_b32 %5, %0\n\t"
            "v_permlane16_swap_b32 %6, %1\n\t"
            "s_nop 0\n\t"
            "v_add_f32 %2, %5, %0\n\t"
            "v_add_f32 %3, %6, %1\n\t"
            "v_mov_b32 %4, %2\n\t"
            "s_nop 0\n\t"
            "v_permlane32_swap_b32 %4, %2\n\t"
            "s_nop 0"
            : "+v"(r01), "+v"(r2v), "=&v"(u01), "=&v"(s2v), "=&v"(A),
              "=&v"(tA), "=&v"(tB));
        s2 = s2v;
        s0 = cnd ? A : u01;                  // off-chain (accel bookkeeping)
        s1 = cnd ? u01 : A;
        float inner = fmaf(cZ_, s2v, PPfull);
        float t = fmaf(cU_, u01, inner);
        return fmaf(cA_, A, t);              // pre_{s+1}
    };

    // ---- prologue ----
    f2 pxy = (f2){state0[0], state0[1]}; float pz = state0[2];
    f2 vxy = (f2){state0[3], state0[4]}; float vz = state0[5];

    float dotpp = dotP(pxy, pz);
    float dotpv = dotP(vxy, vz);
    float dotvv = dotV(vxy, vz);
    float base0 = b1r + dotpp + dotvv;
    f2 PB2xy = fma2(f2s(hd),  vxy, pxy); float PB2z = fmaf(hd,  vz, pz);
    f2 PB4xy = fma2(f2s(dtf), vxy, pxy); float PB4z = fmaf(dtf, vz, pz);
    float PP2raw = fmaf(hd,  dotpv, base0 + CH);
    float PP4raw = fmaf(dtf, dotpv, base0 + CD);
    G3 gsb1 = gravity(pxy, pz);
    f2 gsb1xy = gsb1.xy; float gsb1z = gsb1.z;
    float PP2full = fmaf(hd, dotV(gsb1xy, gsb1z), PP2raw);
    float preS1 = base0;

    for (int m = 0; m < M; ++m) {
        float s0, s1, s2;
        // ---------------- STAGE 1 ----------------
        float pre2 = mlpchain(preS1, PP2full, cAH, cUH, wcH2, s0, s1, s2);
        f2 a1xy = fma2(f2s(scale), (f2){s0, s1}, gsb1xy);
        float a1z = fmaf(scale, s2, gsb1z);
        G3 g2 = gravity(PB2xy, PB2z);
        f2 p3xy = fma2(f2s(hd2), a1xy, PB2xy); float p3z = fmaf(hd2, a1z, PB2z);
        float PP3full = fmaf(hd2, dotP(a1xy, a1z), PP2raw);
        PP3full = fmaf(hd, dotV(g2.xy, g2.z), PP3full);

        // ---------------- STAGE 2 ----------------
        float pre3 = mlpchain(pre2, PP3full, cAH, cUH, wcH2, s0, s1, s2);
        f2 a2xy = fma2(f2s(scale), (f2){s0, s1}, g2.xy);
        float a2z = fmaf(scale, s2, g2.z);
        G3 g3 = gravity(p3xy, p3z);
        f2 p4xy = fma2(f2s(dthd), a2xy, PB4xy); float p4z = fmaf(dthd, a2z, PB4z);
        float PP4full = fmaf(dthd, dotP(a2xy, a2z), PP4raw);
        PP4full = fmaf(dtf, dotV(g3.xy, g3.z), PP4full);

        // ---------------- STAGE 3 ----------------
        float pre4 = mlpchain(pre3, PP4full, cAD, cUD, wcD2, s0, s1, s2);
        f2 a3xy = fma2(f2s(scale), (f2){s0, s1}, g3.xy);
        float a3z = fmaf(scale, s2, g3.z);
        G3 g4 = gravity(p4xy, p4z);
        // t23 = a2+a3; sa = a1+t23; vk = sa+t23  (= a1+2a2+2a3)
        f2 t23xy = a2xy + a3xy;            float t23z = a2z + a3z;
        f2 saxy  = a1xy + t23xy;           float saz  = a1z + t23z;
        f2 vkxy  = saxy + t23xy;           float vkz  = saz + t23z;
        f2 pnxy = fma2(f2s(dt26), saxy, PB4xy); float pnz = fmaf(dt26, saz, PB4z);
        f2 vpxy = fma2(f2s(dt6), vkxy, vxy); float vpz = fmaf(dt6, vkz, vz);
        float dotppn = dotP(pnxy, pnz);
        float PP1full = b1r6 + dotppn + dotV(vpxy, vpz);
        PP1full = fmaf(dt6, dotV(g4.xy, g4.z), PP1full);

        // ---------------- STAGE 4 ----------------
        preS1 = mlpchain(pre4, PP1full, cA6, cU6, wc62, s0, s1, s2);
        f2 a4xy = fma2(f2s(scale), (f2){s0, s1}, g4.xy);
        float a4z = fmaf(scale, s2, g4.z);
        f2 vnxy = fma2(f2s(dt6), a4xy, vpxy); float vnz = fmaf(dt6, a4z, vpz);
        G3 g1n = gravity(pnxy, pnz);
        gsb1xy = g1n.xy; gsb1z = g1n.z;
        PB2xy = fma2(f2s(hd),  vnxy, pnxy); PB2z = fmaf(hd,  vnz, pnz);
        PB4xy = fma2(f2s(dtf), vnxy, pnxy); PB4z = fmaf(dtf, vnz, pnz);
        float dotpv2 = dotP(vnxy, vnz);
        float dotvv2 = dotV(vnxy, vnz);
        float base0n = b1r + dotppn + dotvv2;
        PP2raw = fmaf(hd,  dotpv2, base0n + CH);
        PP4raw = fmaf(dtf, dotpv2, base0n + CD);
        PP2full = fmaf(hd, dotV(gsb1xy, gsb1z), PP2raw);
        vxy = vnxy; vz = vnz;

        if (tid == 0) {
            float2* op = (float2*)(out + (size_t)m * 6);
            op[0] = make_float2(pnxy.x, pnxy.y);
            op[1] = make_float2(pnz, vnxy.x);
            op[2] = make_float2(vnxy.y, vnz);
        }
    }
}

extern "C" void kernel_launch(void* const* d_in, const int* in_sizes, int n_in,
                              void* d_out, int out_size, void* d_ws, size_t ws_size,
                              hipStream_t stream) {
    const float* state0 = (const float*)d_in[0];
    // d_in[1] = eval_times (only its length matters)
    const float* W1 = (const float*)d_in[2];
    const float* b1 = (const float*)d_in[3];
    const float* W2 = (const float*)d_in[4];
    const float* b2 = (const float*)d_in[5];
    const float* W3 = (const float*)d_in[6];
    const float* b3 = (const float*)d_in[7];
    const float* ls = (const float*)d_in[8];
    // d_in[9] = t0 (unused)
    const int* pdt  = (const int*)d_in[10];
    const int M = in_sizes[1];

    node_kernel<<<dim3(1), dim3(64), 0, stream>>>(
        state0, W1, b1, W2, b2, W3, b3, ls, pdt, (float*)d_out, M);
}

// Round 10
// 8613.195 us; speedup vs baseline: 1.0407x; 1.0407x over previous
//
#include <hip/hip_runtime.h>
#include <math.h>

// NeuralODE: sequential RK4 orbit propagation, J2-J5 gravity + tiny MLP.
// Single wave, chain-latency-bound. R10 = R8 base (R9's perm32 handoff
// reverted; readlane tail restored) +
//  (1) stage-head exp2 OFF-CHAIN: e1_next = exp2(PPfull)*(1 + ln2*(wc.s)),
//      exact to (ln2*Delta)^2/2 ~ 2e-9 rel (Delta = wc.s <= ~1e-4); the
//      E=exp2(PPfull) issues during the previous mlpchain. Chain swaps a
//      transcendental for one v_mul; ln2 folded into the wc weights.
//  (2) hazard-nop trims where an interposed op already gives 2 slots.
//  (3) single-mov swap32sum.
// Lane map (R6): o = lid+16*bit4; ibase = 16*bit5; nin = lid+ibase.
// r01 rows: row0(o<16,x) row1(o>=16,x) row2(o<16,y) row3(o>=16,y).

namespace {
constexpr double dMU = 398600.4418;
constexpr double dRE = 6378.137;
constexpr double dJ2 = 0.00108262668;
constexpr double dJ3 = -2.53265648e-06;
constexpr double dJ4 = -1.61962159e-06;
constexpr double dJ5 = -2.27296082e-07;

constexpr float MU_F = (float)dMU;
constexpr float C2_F = (float)(-1.5 * dJ2 * dMU * dRE * dRE);
constexpr float C3_F = (float)(-2.5 * dJ3 * dMU * dRE * dRE * dRE);
constexpr float C4_F = (float)(15.0 / 8.0 * dJ4 * dMU * dRE * dRE * dRE * dRE);
constexpr float C5_F = (float)(3.0 / 8.0 * dJ5 * dMU * dRE * dRE * dRE * dRE * dRE);
constexpr float D5_F = (float)(-(15.0 / 8.0) * dJ5 * dMU * dRE * dRE * dRE * dRE * dRE);
constexpr float IRREF = (float)(1.0 / 7000.0);
constexpr float IVREF = (float)(1.0 / 7.5);
constexpr float AREF  = (float)(7.5 * 7.5 / 7000.0);
constexpr float L2E2  = 2.8853900817779268f;  // 2*log2(e)
constexpr float LN2F  = 0.6931471805599453f;
} // namespace

typedef float f2 __attribute__((ext_vector_type(2)));
__device__ __forceinline__ f2 f2s(float s) { return (f2){s, s}; }
__device__ __forceinline__ f2 fma2(f2 a, f2 b, f2 c) {
    return __builtin_elementwise_fma(a, b, c);
}

template <int CTRL>
__device__ __forceinline__ int roti(int x) {
    return __builtin_amdgcn_update_dpp(0, x, CTRL, 0xf, 0xf, true);
}
// a+b = x[l] + x[l^32]  (verified R3 primitive; orientation-proof sum)
__device__ __forceinline__ float swap32sum(float x) {
    int a; int b = __float_as_int(x);
    asm("v_mov_b32 %0, %1\n\t"
        "s_nop 0\n\t"
        "v_permlane32_swap_b32 %0, %1\n\t"
        "s_nop 0"
        : "=&v"(a), "+v"(b));
    return __int_as_float(a) + __int_as_float(b);
}
__device__ __forceinline__ float rdl(float x, int lane) {
    return __int_as_float(__builtin_amdgcn_readlane(__float_as_int(x), lane));
}

struct G3 { f2 xy; float z; };

__global__ void __launch_bounds__(64, 1)
node_kernel(const float* __restrict__ state0,
            const float* __restrict__ W1, const float* __restrict__ b1,
            const float* __restrict__ W2, const float* __restrict__ b2,
            const float* __restrict__ W3, const float* __restrict__ b3,
            const float* __restrict__ plog_scale,
            const int*  __restrict__ pdt,
            float* __restrict__ out, int M)
{
    const int tid  = (int)threadIdx.x;
    const int lid  = tid & 15;
    const int o    = lid + (((tid >> 4) & 1) << 4);  // output neuron
    const int ibase = ((tid >> 5) & 1) << 4;          // input half base
    const int nin  = lid + ibase;                     // input neuron (L1)

    // dt arrives as a 1-element array; sniff int32 vs float32 bit pattern.
    int db = *pdt;
    float dtf = (db >= 1 && db <= 1000000) ? (float)db : __int_as_float(db);
    const float hd   = 0.5f * dtf;
    const float dt6  = dtf * (1.0f / 6.0f);
    const float hd2  = hd * hd;
    const float dthd = dtf * hd;
    const float dt26 = dtf * dtf * (1.0f / 6.0f);

    const float scale =
        __builtin_amdgcn_exp2f(plog_scale[0] * 1.4426950408889634f) * AREF;

    // W3 column sums (tanh-fold constants)
    float Cx = 0.0f, Cy = 0.0f, Cz = 0.0f;
    for (int i = 0; i < 32; ++i) {
        Cx += W3[i]; Cy += W3[32 + i]; Cz += W3[64 + i];
    }
    // gravity bias: scale*(b3 + C)
    const f2   sbxy = (f2){scale * (b3[0] + Cx), scale * (b3[1] + Cy)};
    const float sbz = scale * (b3[2] + Cz);

    // ---- per-lane weights (pre-scaled by 2*log2e where they feed a tanh) ----
    const float w1p0 = W1[nin * 6 + 0] * (L2E2 * IRREF);
    const float w1p1 = W1[nin * 6 + 1] * (L2E2 * IRREF);
    const float w1p2 = W1[nin * 6 + 2] * (L2E2 * IRREF);
    const float w1v0 = W1[nin * 6 + 3] * (L2E2 * IVREF);
    const float w1v1 = W1[nin * 6 + 4] * (L2E2 * IVREF);
    const float w1v2 = W1[nin * 6 + 5] * (L2E2 * IVREF);
    const float b1r  = b1[nin] * L2E2;

    // self-calibrated DPP rotation source map (within-row lane index)
    int ns1  = roti<0x121>(lid), ns2  = roti<0x122>(lid), ns3  = roti<0x123>(lid);
    int ns4  = roti<0x124>(lid), ns5  = roti<0x125>(lid), ns6  = roti<0x126>(lid);
    int ns7  = roti<0x127>(lid), ns8  = roti<0x128>(lid), ns9  = roti<0x129>(lid);
    int ns10 = roti<0x12A>(lid), ns11 = roti<0x12B>(lid), ns12 = roti<0x12C>(lid);
    int ns13 = roti<0x12D>(lid), ns14 = roti<0x12E>(lid), ns15 = roti<0x12F>(lid);
    const float* W2r = W2 + o * 32 + ibase;
    const float NW = -2.0f * L2E2;   // negated-doubled (tanh fma absorbed)
    float w2n[16];
    w2n[0]  = W2r[lid]  * NW;
    w2n[1]  = W2r[ns1]  * NW;  w2n[2]  = W2r[ns2]  * NW;
    w2n[3]  = W2r[ns3]  * NW;  w2n[4]  = W2r[ns4]  * NW;
    w2n[5]  = W2r[ns5]  * NW;  w2n[6]  = W2r[ns6]  * NW;
    w2n[7]  = W2r[ns7]  * NW;  w2n[8]  = W2r[ns8]  * NW;
    w2n[9]  = W2r[ns9]  * NW;  w2n[10] = W2r[ns10] * NW;
    w2n[11] = W2r[ns11] * NW;  w2n[12] = W2r[ns12] * NW;
    w2n[13] = W2r[ns13] * NW;  w2n[14] = W2r[ns14] * NW;
    w2n[15] = W2r[ns15] * NW;
    // b2h: 0.5*L2E2*(b2[o] + full W2 row sum); swap32 doubles it back.
    float rowsum = 0.0f;
    for (int k = 0; k < 32; ++k) rowsum += W2[o * 32 + k];
    const float b2h = (b2[o] + rowsum) * (0.5f * L2E2);
    // L3 negated-doubled weights (x on ibase=0 half, y on ibase=16 half; z all)
    const float w3xyn = -2.0f * ((ibase == 0) ? W3[o] : W3[32 + o]);
    const float w3zn  = -2.0f * W3[64 + o];

    // chain-out weights: ln2 * scale * dt-coef * w1v  (feed the 1+ln2*Delta
    // first-order exp factor; accel bookkeeping still uses raw s0,s1,s2)
    const float lH0 = (LN2F * scale * hd)  * w1v0,
                lH1 = (LN2F * scale * hd)  * w1v1,
                lH2 = (LN2F * scale * hd)  * w1v2;
    const float lD0 = (LN2F * scale * dtf) * w1v0,
                lD1 = (LN2F * scale * dtf) * w1v1,
                lD2 = (LN2F * scale * dtf) * w1v2;
    const float l60 = (LN2F * scale * dt6) * w1v0,
                l61 = (LN2F * scale * dt6) * w1v1,
                l62 = (LN2F * scale * dt6) * w1v2;
    // handoff constant folds: CH/CD/C6 = dt-weight * scale * (w1v . C)
    const float dCv = scale * (w1v0 * Cx + w1v1 * Cy + w1v2 * Cz);
    const float CH = hd * dCv, CD = dtf * dCv, C6 = dt6 * dCv;
    const float b1r6 = b1r + C6;

    auto dotP = [&](f2 xy, float z) {
        return fmaf(w1p2, z, fmaf(w1p1, xy.y, w1p0 * xy.x));
    };
    auto dotV = [&](f2 xy, float z) {
        return fmaf(w1v2, z, fmaf(w1v1, xy.y, w1v0 * xy.x));
    };

    // gravity with scale*(b3+C) folded in: returns g + sb'.
    auto gravity = [&](f2 pxy, float pz) -> G3 {
        float zz = pz * pz;
        float r2 = fmaf(pxy.x, pxy.x, fmaf(pxy.y, pxy.y, zz));
        float ir = __builtin_amdgcn_rsqf(r2);
        float ir2 = ir * ir, ir3 = ir2 * ir;
        float s  = zz * ir2;
        float s2 = s * s;
        f2 qp  = fma2(f2s(-5.0f), f2s(s), (f2){1.0f, 3.0f});
        f2 p4p = fma2(f2s(21.0f), f2s(s2),
                      fma2((f2){-14.0f, -70.0f / 3.0f}, f2s(s), (f2){1.0f, 5.0f}));
        f2 p5p = fma2(f2s(231.0f), f2s(s2),
                      fma2((f2){-210.0f, -315.0f}, f2s(s), (f2){35.0f, 105.0f}));
        f2 t3p = fma2(f2s(-7.0f), f2s(s), (f2){3.0f, 6.0f});
        float t3  = pz * t3p.x;
        float p3z = fmaf(s, t3p.y, -0.6f);
        float t5  = pz * p5p.x;
        f2 inner = (f2){fmaf(C3_F, t3, C4_F * p4p.x), C4_F * p4p.y};
        f2 H = fma2(f2s(ir2), (f2){C5_F * t5, 0.0f}, inner);
        H = fma2(f2s(ir2), H, f2s(C2_F) * qp);
        H = fma2(f2s(ir2), H, f2s(-MU_F));
        float Gxy = ir3 * H.x;
        float ir5 = ir3 * ir2;
        float w = fmaf(C5_F, s * p5p.y, D5_F);
        w = fmaf(ir2, w, C3_F * p3z);
        G3 g;
        g.xy = fma2(pxy, f2s(Gxy), sbxy);
        g.z  = fmaf(pz * ir3, H.y, fmaf(ir5, w, sbz));
        return g;
    };

    // MLP chain, entered with e1 = 2^(pre) already formed.
    // Outputs red0/red1 (SGPR) and red2 (uniform VGPR) = -2*sum(w3 . rc2)
    // (constant parts folded into biases upstream).
    auto mlpchain = [&](float e1, float& red0, float& red1, float& red2) {
        float rc1 = __builtin_amdgcn_rcpf(e1 + 1.0f);   // tanh = 1-2rc (folded)
        float a0 = fmaf(rc1, w2n[0], b2h);
        float a1, a2, a3;
        // 15 DPP-fused MACs; a0-fma + s_nop 0 = 2 slots for the DPP hazard.
        asm("s_nop 0\n\t"
            "v_mul_f32_dpp %1, %4, %5 row_ror:1 row_mask:0xf bank_mask:0xf\n\t"
            "v_mul_f32_dpp %2, %4, %6 row_ror:2 row_mask:0xf bank_mask:0xf\n\t"
            "v_mul_f32_dpp %3, %4, %7 row_ror:3 row_mask:0xf bank_mask:0xf\n\t"
            "v_fmac_f32_dpp %0, %4, %8 row_ror:4 row_mask:0xf bank_mask:0xf\n\t"
            "v_fmac_f32_dpp %1, %4, %9 row_ror:5 row_mask:0xf bank_mask:0xf\n\t"
            "v_fmac_f32_dpp %2, %4, %10 row_ror:6 row_mask:0xf bank_mask:0xf\n\t"
            "v_fmac_f32_dpp %3, %4, %11 row_ror:7 row_mask:0xf bank_mask:0xf\n\t"
            "v_fmac_f32_dpp %0, %4, %12 row_ror:8 row_mask:0xf bank_mask:0xf\n\t"
            "v_fmac_f32_dpp %1, %4, %13 row_ror:9 row_mask:0xf bank_mask:0xf\n\t"
            "v_fmac_f32_dpp %2, %4, %14 row_ror:10 row_mask:0xf bank_mask:0xf\n\t"
            "v_fmac_f32_dpp %3, %4, %15 row_ror:11 row_mask:0xf bank_mask:0xf\n\t"
            "v_fmac_f32_dpp %0, %4, %16 row_ror:12 row_mask:0xf bank_mask:0xf\n\t"
            "v_fmac_f32_dpp %1, %4, %17 row_ror:13 row_mask:0xf bank_mask:0xf\n\t"
            "v_fmac_f32_dpp %2, %4, %18 row_ror:14 row_mask:0xf bank_mask:0xf\n\t"
            "v_fmac_f32_dpp %3, %4, %19 row_ror:15 row_mask:0xf bank_mask:0xf"
            : "+v"(a0), "=&v"(a1), "=&v"(a2), "=&v"(a3)
            : "v"(rc1),
              "v"(w2n[1]), "v"(w2n[2]), "v"(w2n[3]), "v"(w2n[4]),
              "v"(w2n[5]), "v"(w2n[6]), "v"(w2n[7]), "v"(w2n[8]),
              "v"(w2n[9]), "v"(w2n[10]), "v"(w2n[11]), "v"(w2n[12]),
              "v"(w2n[13]), "v"(w2n[14]), "v"(w2n[15]));
        float accA = (a0 + a2) + (a1 + a3);
        float pre2 = swap32sum(accA);        // + other input half
        float e2  = __builtin_amdgcn_exp2f(pre2);
        float rc2 = __builtin_amdgcn_rcpf(e2 + 1.0f);
        float r01 = w3xyn * rc2;             // x rows0,1 ; y rows2,3
        float r2v = w3zn  * rc2;             // z halves within each 32-half
        float tA, tB;
        // rowsums -> perm16 self-sums (r2v-mul + s_nop 0 = 2 slots at head).
        asm("s_nop 0\n\t"
            "v_add_f32_dpp %0, %0, %0 row_ror:1 row_mask:0xf bank_mask:0xf\n\t"
            "v_add_f32_dpp %1, %1, %1 row_ror:1 row_mask:0xf bank_mask:0xf\n\t"
            "v_add_f32_dpp %0, %0, %0 row_ror:2 row_mask:0xf bank_mask:0xf\n\t"
            "v_add_f32_dpp %1, %1, %1 row_ror:2 row_mask:0xf bank_mask:0xf\n\t"
            "v_add_f32_dpp %0, %0, %0 row_ror:4 row_mask:0xf bank_mask:0xf\n\t"
            "v_add_f32_dpp %1, %1, %1 row_ror:4 row_mask:0xf bank_mask:0xf\n\t"
            "v_add_f32_dpp %0, %0, %0 row_ror:8 row_mask:0xf bank_mask:0xf\n\t"
            "v_add_f32_dpp %1, %1, %1 row_ror:8 row_mask:0xf bank_mask:0xf\n\t"
            "v_mov_b32 %2, %0\n\t"
            "v_mov_b32 %3, %1\n\t"
            "s_nop 0\n\t"
            "v_permlane16_swap_b32 %2, %0\n\t"
            "v_permlane16_swap_b32 %3, %1\n\t"
            "s_nop 0"
            : "+v"(r01), "+v"(r2v), "=&v"(tA), "=&v"(tB));
        float u01 = tA + r01;
        red2 = tB + r2v;                     // VGPR, uniform
        red0 = rdl(u01, 0);                  // x-reduction (SGPR)
        red1 = rdl(u01, 32);                 // y-reduction (SGPR)
    };

    // ---- prologue ----
    f2 pxy = (f2){state0[0], state0[1]}; float pz = state0[2];
    f2 vxy = (f2){state0[3], state0[4]}; float vz = state0[5];

    float dotpp = dotP(pxy, pz);
    float dotpv = dotP(vxy, vz);
    float dotvv = dotV(vxy, vz);
    float base0 = b1r + dotpp + dotvv;
    f2 PB2xy = fma2(f2s(hd),  vxy, pxy); float PB2z = fmaf(hd,  vz, pz);
    f2 PB4xy = fma2(f2s(dtf), vxy, pxy); float PB4z = fmaf(dtf, vz, pz);
    float PP2raw = fmaf(hd,  dotpv, base0 + CH);
    float PP4raw = fmaf(dtf, dotpv, base0 + CD);
    G3 gsb1 = gravity(pxy, pz);
    f2 gsb1xy = gsb1.xy; float gsb1z = gsb1.z;
    float PP2full = fmaf(hd, dotV(gsb1xy, gsb1z), PP2raw);
    float e1S1 = __builtin_amdgcn_exp2f(base0);
    float E2   = __builtin_amdgcn_exp2f(PP2full);

    for (int m = 0; m < M; ++m) {
        float s0, s1, s2;
        // ---------------- STAGE 1 ----------------
        mlpchain(e1S1, s0, s1, s2);
        // e1 for stage 2: E2 * (1 + ln2*(wc.s))  [first-order exact, err~2e-9]
        float q2 = fmaf(lH1, s1, fmaf(lH0, s0, fmaf(lH2, s2, 1.0f)));
        float e1S2 = E2 * q2;
        f2 a1xy = fma2(f2s(scale), (f2){s0, s1}, gsb1xy);
        float a1z = fmaf(scale, s2, gsb1z);
        G3 g2 = gravity(PB2xy, PB2z);
        f2 p3xy = fma2(f2s(hd2), a1xy, PB2xy); float p3z = fmaf(hd2, a1z, PB2z);
        float PP3full = fmaf(hd2, dotP(a1xy, a1z), PP2raw);
        PP3full = fmaf(hd, dotV(g2.xy, g2.z), PP3full);
        float E3 = __builtin_amdgcn_exp2f(PP3full);     // off-chain

        // ---------------- STAGE 2 ----------------
        mlpchain(e1S2, s0, s1, s2);
        float q3 = fmaf(lH1, s1, fmaf(lH0, s0, fmaf(lH2, s2, 1.0f)));
        float e1S3 = E3 * q3;
        f2 a2xy = fma2(f2s(scale), (f2){s0, s1}, g2.xy);
        float a2z = fmaf(scale, s2, g2.z);
        G3 g3 = gravity(p3xy, p3z);
        f2 p4xy = fma2(f2s(dthd), a2xy, PB4xy); float p4z = fmaf(dthd, a2z, PB4z);
        float PP4full = fmaf(dthd, dotP(a2xy, a2z), PP4raw);
        PP4full = fmaf(dtf, dotV(g3.xy, g3.z), PP4full);
        float E4 = __builtin_amdgcn_exp2f(PP4full);     // off-chain

        // ---------------- STAGE 3 ----------------
        mlpchain(e1S3, s0, s1, s2);
        float q4 = fmaf(lD1, s1, fmaf(lD0, s0, fmaf(lD2, s2, 1.0f)));
        float e1S4 = E4 * q4;
        f2 a3xy = fma2(f2s(scale), (f2){s0, s1}, g3.xy);
        float a3z = fmaf(scale, s2, g3.z);
        G3 g4 = gravity(p4xy, p4z);
        // t23 = a2+a3; sa = a1+t23; vk = sa+t23  (= a1+2a2+2a3)
        f2 t23xy = a2xy + a3xy;            float t23z = a2z + a3z;
        f2 saxy  = a1xy + t23xy;           float saz  = a1z + t23z;
        f2 vkxy  = saxy + t23xy;           float vkz  = saz + t23z;
        f2 pnxy = fma2(f2s(dt26), saxy, PB4xy); float pnz = fmaf(dt26, saz, PB4z);
        f2 vpxy = fma2(f2s(dt6), vkxy, vxy); float vpz = fmaf(dt6, vkz, vz);
        float dotppn = dotP(pnxy, pnz);
        float PP1full = b1r6 + dotppn + dotV(vpxy, vpz);
        PP1full = fmaf(dt6, dotV(g4.xy, g4.z), PP1full);
        float E1n = __builtin_amdgcn_exp2f(PP1full);    // off-chain

        // ---------------- STAGE 4 ----------------
        mlpchain(e1S4, s0, s1, s2);
        float q1 = fmaf(l61, s1, fmaf(l60, s0, fmaf(l62, s2, 1.0f)));
        e1S1 = E1n * q1;
        f2 a4xy = fma2(f2s(scale), (f2){s0, s1}, g4.xy);
        float a4z = fmaf(scale, s2, g4.z);
        f2 vnxy = fma2(f2s(dt6), a4xy, vpxy); float vnz = fmaf(dt6, a4z, vpz);
        G3 g1n = gravity(pnxy, pnz);
        gsb1xy = g1n.xy; gsb1z = g1n.z;
        PB2xy = fma2(f2s(hd),  vnxy, pnxy); PB2z = fmaf(hd,  vnz, pnz);
        PB4xy = fma2(f2s(dtf), vnxy, pnxy); PB4z = fmaf(dtf, vnz, pnz);
        float dotpv2 = dotP(vnxy, vnz);
        float dotvv2 = dotV(vnxy, vnz);
        float base0n = b1r + dotppn + dotvv2;
        PP2raw = fmaf(hd,  dotpv2, base0n + CH);
        PP4raw = fmaf(dtf, dotpv2, base0n + CD);
        PP2full = fmaf(hd, dotV(gsb1xy, gsb1z), PP2raw);
        E2 = __builtin_amdgcn_exp2f(PP2full);           // off-chain (next iter)
        vxy = vnxy; vz = vnz;

        if (tid == 0) {
            float2* op = (float2*)(out + (size_t)m * 6);
            op[0] = make_float2(pnxy.x, pnxy.y);
            op[1] = make_float2(pnz, vnxy.x);
            op[2] = make_float2(vnxy.y, vnz);
        }
    }
}

extern "C" void kernel_launch(void* const* d_in, const int* in_sizes, int n_in,
                              void* d_out, int out_size, void* d_ws, size_t ws_size,
                              hipStream_t stream) {
    const float* state0 = (const float*)d_in[0];
    // d_in[1] = eval_times (only its length matters)
    const float* W1 = (const float*)d_in[2];
    const float* b1 = (const float*)d_in[3];
    const float* W2 = (const float*)d_in[4];
    const float* b2 = (const float*)d_in[5];
    const float* W3 = (const float*)d_in[6];
    const float* b3 = (const float*)d_in[7];
    const float* ls = (const float*)d_in[8];
    // d_in[9] = t0 (unused)
    const int* pdt  = (const int*)d_in[10];
    const int M = in_sizes[1];

    node_kernel<<<dim3(1), dim3(64), 0, stream>>>(
        state0, W1, b1, W2, b2, W3, b3, ls, pdt, (float*)d_out, M);
}

// Round 11
// 8528.525 us; speedup vs baseline: 1.0510x; 1.0099x over previous
//
#include <hip/hip_runtime.h>
#include <math.h>

// NeuralODE: sequential RK4 orbit propagation, J2-J5 gravity + tiny MLP.
// Single wave, chain-latency-bound. R11 = R8 restored verbatim (best: 8532us).
// R7 (perm-L3), R9 (perm32 handoff), R10 (off-chain exp2 + nop trims) all
// regressed -- the readlane tail + on-chain exp2 structure of R8 is the
// measured optimum of this family.
//  (1) tanh final-fmas absorbed into negated-doubled weights + constant folds
//      (rowsums into b2h; W3 colsums C into gravity bias and handoff bases).
//  (2) L3: 4 ror-adds then ONE permlane16 self-sum -> x-red on lanes<32,
//      y-red on lanes>=32, z-red uniform in VGPR; only 2 readlanes left.
//  (3) t23 accumulation refactor.
// Lane map (R6): o = lid+16*bit4 (output neuron); ibase = 16*bit5; nin =
// lid+ibase (L1 neuron). r01 rows: row0(o<16,x) row1(o>=16,x) row2(o<16,y)
// row3(o>=16,y); z-dot complete within each 32-half.

namespace {
constexpr double dMU = 398600.4418;
constexpr double dRE = 6378.137;
constexpr double dJ2 = 0.00108262668;
constexpr double dJ3 = -2.53265648e-06;
constexpr double dJ4 = -1.61962159e-06;
constexpr double dJ5 = -2.27296082e-07;

constexpr float MU_F = (float)dMU;
constexpr float C2_F = (float)(-1.5 * dJ2 * dMU * dRE * dRE);
constexpr float C3_F = (float)(-2.5 * dJ3 * dMU * dRE * dRE * dRE);
constexpr float C4_F = (float)(15.0 / 8.0 * dJ4 * dMU * dRE * dRE * dRE * dRE);
constexpr float C5_F = (float)(3.0 / 8.0 * dJ5 * dMU * dRE * dRE * dRE * dRE * dRE);
constexpr float D5_F = (float)(-(15.0 / 8.0) * dJ5 * dMU * dRE * dRE * dRE * dRE * dRE);
constexpr float IRREF = (float)(1.0 / 7000.0);
constexpr float IVREF = (float)(1.0 / 7.5);
constexpr float AREF  = (float)(7.5 * 7.5 / 7000.0);
constexpr float L2E2  = 2.8853900817779268f;  // 2*log2(e)
} // namespace

typedef float f2 __attribute__((ext_vector_type(2)));
__device__ __forceinline__ f2 f2s(float s) { return (f2){s, s}; }
__device__ __forceinline__ f2 fma2(f2 a, f2 b, f2 c) {
    return __builtin_elementwise_fma(a, b, c);
}

template <int CTRL>
__device__ __forceinline__ int roti(int x) {
    return __builtin_amdgcn_update_dpp(0, x, CTRL, 0xf, 0xf, true);
}
// a+b = x[l] + x[l^32]  (verified R3 primitive; orientation-proof sum)
__device__ __forceinline__ float swap32sum(float x) {
    int a = __float_as_int(x), b = __float_as_int(x);
    asm("s_nop 0\n\tv_permlane32_swap_b32 %0, %1\n\ts_nop 0"
        : "+v"(a), "+v"(b));
    return __int_as_float(a) + __int_as_float(b);
}
__device__ __forceinline__ float rdl(float x, int lane) {
    return __int_as_float(__builtin_amdgcn_readlane(__float_as_int(x), lane));
}

struct G3 { f2 xy; float z; };

__global__ void __launch_bounds__(64, 1)
node_kernel(const float* __restrict__ state0,
            const float* __restrict__ W1, const float* __restrict__ b1,
            const float* __restrict__ W2, const float* __restrict__ b2,
            const float* __restrict__ W3, const float* __restrict__ b3,
            const float* __restrict__ plog_scale,
            const int*  __restrict__ pdt,
            float* __restrict__ out, int M)
{
    const int tid  = (int)threadIdx.x;
    const int lid  = tid & 15;
    const int o    = lid + (((tid >> 4) & 1) << 4);  // output neuron
    const int ibase = ((tid >> 5) & 1) << 4;          // input half base
    const int nin  = lid + ibase;                     // input neuron (L1)

    // dt arrives as a 1-element array; sniff int32 vs float32 bit pattern.
    int db = *pdt;
    float dtf = (db >= 1 && db <= 1000000) ? (float)db : __int_as_float(db);
    const float hd   = 0.5f * dtf;
    const float dt6  = dtf * (1.0f / 6.0f);
    const float hd2  = hd * hd;
    const float dthd = dtf * hd;
    const float dt26 = dtf * dtf * (1.0f / 6.0f);

    const float scale =
        __builtin_amdgcn_exp2f(plog_scale[0] * 1.4426950408889634f) * AREF;

    // W3 column sums (tanh-fold constants)
    float Cx = 0.0f, Cy = 0.0f, Cz = 0.0f;
    for (int i = 0; i < 32; ++i) {
        Cx += W3[i]; Cy += W3[32 + i]; Cz += W3[64 + i];
    }
    // gravity bias: scale*(b3 + C)
    const f2   sbxy = (f2){scale * (b3[0] + Cx), scale * (b3[1] + Cy)};
    const float sbz = scale * (b3[2] + Cz);

    // ---- per-lane weights (pre-scaled by 2*log2e where they feed a tanh) ----
    const float w1p0 = W1[nin * 6 + 0] * (L2E2 * IRREF);
    const float w1p1 = W1[nin * 6 + 1] * (L2E2 * IRREF);
    const float w1p2 = W1[nin * 6 + 2] * (L2E2 * IRREF);
    const float w1v0 = W1[nin * 6 + 3] * (L2E2 * IVREF);
    const float w1v1 = W1[nin * 6 + 4] * (L2E2 * IVREF);
    const float w1v2 = W1[nin * 6 + 5] * (L2E2 * IVREF);
    const float b1r  = b1[nin] * L2E2;

    // self-calibrated DPP rotation source map (within-row lane index)
    int ns1  = roti<0x121>(lid), ns2  = roti<0x122>(lid), ns3  = roti<0x123>(lid);
    int ns4  = roti<0x124>(lid), ns5  = roti<0x125>(lid), ns6  = roti<0x126>(lid);
    int ns7  = roti<0x127>(lid), ns8  = roti<0x128>(lid), ns9  = roti<0x129>(lid);
    int ns10 = roti<0x12A>(lid), ns11 = roti<0x12B>(lid), ns12 = roti<0x12C>(lid);
    int ns13 = roti<0x12D>(lid), ns14 = roti<0x12E>(lid), ns15 = roti<0x12F>(lid);
    const float* W2r = W2 + o * 32 + ibase;
    const float NW = -2.0f * L2E2;   // negated-doubled (tanh fma absorbed)
    float w2n[16];
    w2n[0]  = W2r[lid]  * NW;
    w2n[1]  = W2r[ns1]  * NW;  w2n[2]  = W2r[ns2]  * NW;
    w2n[3]  = W2r[ns3]  * NW;  w2n[4]  = W2r[ns4]  * NW;
    w2n[5]  = W2r[ns5]  * NW;  w2n[6]  = W2r[ns6]  * NW;
    w2n[7]  = W2r[ns7]  * NW;  w2n[8]  = W2r[ns8]  * NW;
    w2n[9]  = W2r[ns9]  * NW;  w2n[10] = W2r[ns10] * NW;
    w2n[11] = W2r[ns11] * NW;  w2n[12] = W2r[ns12] * NW;
    w2n[13] = W2r[ns13] * NW;  w2n[14] = W2r[ns14] * NW;
    w2n[15] = W2r[ns15] * NW;
    // b2h: 0.5*L2E2*(b2[o] + full W2 row sum); swap32 doubles it back.
    float rowsum = 0.0f;
    for (int k = 0; k < 32; ++k) rowsum += W2[o * 32 + k];
    const float b2h = (b2[o] + rowsum) * (0.5f * L2E2);
    // L3 negated-doubled weights (x on ibase=0 half, y on ibase=16 half; z all)
    const float w3xyn = -2.0f * ((ibase == 0) ? W3[o] : W3[32 + o]);
    const float w3zn  = -2.0f * W3[64 + o];

    // chain-out weight vectors (scale premultiplied)
    const float wcH0 = (scale * hd)  * w1v0, wcH1 = (scale * hd)  * w1v1,
                wcH2 = (scale * hd)  * w1v2;
    const float wcD0 = (scale * dtf) * w1v0, wcD1 = (scale * dtf) * w1v1,
                wcD2 = (scale * dtf) * w1v2;
    const float wc60 = (scale * dt6) * w1v0, wc61 = (scale * dt6) * w1v1,
                wc62 = (scale * dt6) * w1v2;
    // handoff constant folds: CH/CD/C6 = dt-weight * scale * (w1v . C)
    const float dCv = scale * (w1v0 * Cx + w1v1 * Cy + w1v2 * Cz);
    const float CH = hd * dCv, CD = dtf * dCv, C6 = dt6 * dCv;
    const float b1r6 = b1r + C6;

    auto dotP = [&](f2 xy, float z) {
        return fmaf(w1p2, z, fmaf(w1p1, xy.y, w1p0 * xy.x));
    };
    auto dotV = [&](f2 xy, float z) {
        return fmaf(w1v2, z, fmaf(w1v1, xy.y, w1v0 * xy.x));
    };

    // gravity with scale*(b3+C) folded in: returns g + sb'.
    auto gravity = [&](f2 pxy, float pz) -> G3 {
        float zz = pz * pz;
        float r2 = fmaf(pxy.x, pxy.x, fmaf(pxy.y, pxy.y, zz));
        float ir = __builtin_amdgcn_rsqf(r2);
        float ir2 = ir * ir, ir3 = ir2 * ir;
        float s  = zz * ir2;
        float s2 = s * s;
        f2 qp  = fma2(f2s(-5.0f), f2s(s), (f2){1.0f, 3.0f});
        f2 p4p = fma2(f2s(21.0f), f2s(s2),
                      fma2((f2){-14.0f, -70.0f / 3.0f}, f2s(s), (f2){1.0f, 5.0f}));
        f2 p5p = fma2(f2s(231.0f), f2s(s2),
                      fma2((f2){-210.0f, -315.0f}, f2s(s), (f2){35.0f, 105.0f}));
        f2 t3p = fma2(f2s(-7.0f), f2s(s), (f2){3.0f, 6.0f});
        float t3  = pz * t3p.x;
        float p3z = fmaf(s, t3p.y, -0.6f);
        float t5  = pz * p5p.x;
        f2 inner = (f2){fmaf(C3_F, t3, C4_F * p4p.x), C4_F * p4p.y};
        f2 H = fma2(f2s(ir2), (f2){C5_F * t5, 0.0f}, inner);
        H = fma2(f2s(ir2), H, f2s(C2_F) * qp);
        H = fma2(f2s(ir2), H, f2s(-MU_F));
        float Gxy = ir3 * H.x;
        float ir5 = ir3 * ir2;
        float w = fmaf(C5_F, s * p5p.y, D5_F);
        w = fmaf(ir2, w, C3_F * p3z);
        G3 g;
        g.xy = fma2(pxy, f2s(Gxy), sbxy);
        g.z  = fmaf(pz * ir3, H.y, fmaf(ir5, w, sbz));
        return g;
    };

    // MLP chain: pre(scaled) -> red0,red1 (SGPR; -2*sum(W3x.rc2), etc.) and
    // red2 (VGPR, uniform all lanes). Consumers add the folded C constants.
    auto mlpchain = [&](float pre, float& red0, float& red1, float& red2) {
        float e1  = __builtin_amdgcn_exp2f(pre);
        float rc1 = __builtin_amdgcn_rcpf(e1 + 1.0f);   // tanh = 1-2rc (folded)
        float a0 = fmaf(rc1, w2n[0], b2h);
        float a1, a2, a3;
        // 15 DPP-fused MACs; s_nop 1 covers VALU-write(rc1) -> DPP-read hazard.
        asm("s_nop 1\n\t"
            "v_mul_f32_dpp %1, %4, %5 row_ror:1 row_mask:0xf bank_mask:0xf\n\t"
            "v_mul_f32_dpp %2, %4, %6 row_ror:2 row_mask:0xf bank_mask:0xf\n\t"
            "v_mul_f32_dpp %3, %4, %7 row_ror:3 row_mask:0xf bank_mask:0xf\n\t"
            "v_fmac_f32_dpp %0, %4, %8 row_ror:4 row_mask:0xf bank_mask:0xf\n\t"
            "v_fmac_f32_dpp %1, %4, %9 row_ror:5 row_mask:0xf bank_mask:0xf\n\t"
            "v_fmac_f32_dpp %2, %4, %10 row_ror:6 row_mask:0xf bank_mask:0xf\n\t"
            "v_fmac_f32_dpp %3, %4, %11 row_ror:7 row_mask:0xf bank_mask:0xf\n\t"
            "v_fmac_f32_dpp %0, %4, %12 row_ror:8 row_mask:0xf bank_mask:0xf\n\t"
            "v_fmac_f32_dpp %1, %4, %13 row_ror:9 row_mask:0xf bank_mask:0xf\n\t"
            "v_fmac_f32_dpp %2, %4, %14 row_ror:10 row_mask:0xf bank_mask:0xf\n\t"
            "v_fmac_f32_dpp %3, %4, %15 row_ror:11 row_mask:0xf bank_mask:0xf\n\t"
            "v_fmac_f32_dpp %0, %4, %16 row_ror:12 row_mask:0xf bank_mask:0xf\n\t"
            "v_fmac_f32_dpp %1, %4, %17 row_ror:13 row_mask:0xf bank_mask:0xf\n\t"
            "v_fmac_f32_dpp %2, %4, %18 row_ror:14 row_mask:0xf bank_mask:0xf\n\t"
            "v_fmac_f32_dpp %3, %4, %19 row_ror:15 row_mask:0xf bank_mask:0xf"
            : "+v"(a0), "=&v"(a1), "=&v"(a2), "=&v"(a3)
            : "v"(rc1),
              "v"(w2n[1]), "v"(w2n[2]), "v"(w2n[3]), "v"(w2n[4]),
              "v"(w2n[5]), "v"(w2n[6]), "v"(w2n[7]), "v"(w2n[8]),
              "v"(w2n[9]), "v"(w2n[10]), "v"(w2n[11]), "v"(w2n[12]),
              "v"(w2n[13]), "v"(w2n[14]), "v"(w2n[15]));
        float accA = (a0 + a2) + (a1 + a3);
        float pre2 = swap32sum(accA);        // + other input half
        float e2  = __builtin_amdgcn_exp2f(pre2);
        float rc2 = __builtin_amdgcn_rcpf(e2 + 1.0f);
        float r01 = w3xyn * rc2;             // x rows0,1 ; y rows2,3
        float r2v = w3zn  * rc2;             // z complete in each 32-half
        float tA, tB;
        // 4 ror-adds (rowsums) then permlane16 self-sum: u01 = rows0+1 (x) on
        // lanes<32 / rows2+3 (y) on lanes>=32; red2 uniform on all lanes.
        asm("s_nop 1\n\t"
            "v_add_f32_dpp %0, %0, %0 row_ror:1 row_mask:0xf bank_mask:0xf\n\t"
            "v_add_f32_dpp %1, %1, %1 row_ror:1 row_mask:0xf bank_mask:0xf\n\t"
            "v_add_f32_dpp %0, %0, %0 row_ror:2 row_mask:0xf bank_mask:0xf\n\t"
            "v_add_f32_dpp %1, %1, %1 row_ror:2 row_mask:0xf bank_mask:0xf\n\t"
            "v_add_f32_dpp %0, %0, %0 row_ror:4 row_mask:0xf bank_mask:0xf\n\t"
            "v_add_f32_dpp %1, %1, %1 row_ror:4 row_mask:0xf bank_mask:0xf\n\t"
            "v_add_f32_dpp %0, %0, %0 row_ror:8 row_mask:0xf bank_mask:0xf\n\t"
            "v_add_f32_dpp %1, %1, %1 row_ror:8 row_mask:0xf bank_mask:0xf\n\t"
            "v_mov_b32 %2, %0\n\t"
            "v_mov_b32 %3, %1\n\t"
            "s_nop 0\n\t"
            "v_permlane16_swap_b32 %2, %0\n\t"
            "v_permlane16_swap_b32 %3, %1\n\t"
            "s_nop 0"
            : "+v"(r01), "+v"(r2v), "=&v"(tA), "=&v"(tB));
        float u01 = tA + r01;
        red2 = tB + r2v;                     // VGPR, uniform
        red0 = rdl(u01, 0);                  // x-reduction (SGPR)
        red1 = rdl(u01, 32);                 // y-reduction (SGPR)
    };

    // ---- prologue ----
    f2 pxy = (f2){state0[0], state0[1]}; float pz = state0[2];
    f2 vxy = (f2){state0[3], state0[4]}; float vz = state0[5];

    float dotpp = dotP(pxy, pz);
    float dotpv = dotP(vxy, vz);
    float dotvv = dotV(vxy, vz);
    float base0 = b1r + dotpp + dotvv;
    f2 PB2xy = fma2(f2s(hd),  vxy, pxy); float PB2z = fmaf(hd,  vz, pz);
    f2 PB4xy = fma2(f2s(dtf), vxy, pxy); float PB4z = fmaf(dtf, vz, pz);
    float PP2raw = fmaf(hd,  dotpv, base0 + CH);
    float PP4raw = fmaf(dtf, dotpv, base0 + CD);
    G3 gsb1 = gravity(pxy, pz);
    f2 gsb1xy = gsb1.xy; float gsb1z = gsb1.z;
    float PP2full = fmaf(hd, dotV(gsb1xy, gsb1z), PP2raw);
    float preS1 = base0;

    for (int m = 0; m < M; ++m) {
        float s0, s1, s2;
        // ---------------- STAGE 1 ----------------
        mlpchain(preS1, s0, s1, s2);
        float pre2 = fmaf(wcH1, s1, fmaf(wcH0, s0, fmaf(wcH2, s2, PP2full)));
        f2 a1xy = fma2(f2s(scale), (f2){s0, s1}, gsb1xy);
        float a1z = fmaf(scale, s2, gsb1z);
        G3 g2 = gravity(PB2xy, PB2z);
        f2 p3xy = fma2(f2s(hd2), a1xy, PB2xy); float p3z = fmaf(hd2, a1z, PB2z);
        float PP3full = fmaf(hd2, dotP(a1xy, a1z), PP2raw);
        PP3full = fmaf(hd, dotV(g2.xy, g2.z), PP3full);

        // ---------------- STAGE 2 ----------------
        mlpchain(pre2, s0, s1, s2);
        float pre3 = fmaf(wcH1, s1, fmaf(wcH0, s0, fmaf(wcH2, s2, PP3full)));
        f2 a2xy = fma2(f2s(scale), (f2){s0, s1}, g2.xy);
        float a2z = fmaf(scale, s2, g2.z);
        G3 g3 = gravity(p3xy, p3z);
        f2 p4xy = fma2(f2s(dthd), a2xy, PB4xy); float p4z = fmaf(dthd, a2z, PB4z);
        float PP4full = fmaf(dthd, dotP(a2xy, a2z), PP4raw);
        PP4full = fmaf(dtf, dotV(g3.xy, g3.z), PP4full);

        // ---------------- STAGE 3 ----------------
        mlpchain(pre3, s0, s1, s2);
        float pre4 = fmaf(wcD1, s1, fmaf(wcD0, s0, fmaf(wcD2, s2, PP4full)));
        f2 a3xy = fma2(f2s(scale), (f2){s0, s1}, g3.xy);
        float a3z = fmaf(scale, s2, g3.z);
        G3 g4 = gravity(p4xy, p4z);
        // t23 = a2+a3; sa = a1+t23; vk = sa+t23  (= a1+2a2+2a3)
        f2 t23xy = a2xy + a3xy;            float t23z = a2z + a3z;
        f2 saxy  = a1xy + t23xy;           float saz  = a1z + t23z;
        f2 vkxy  = saxy + t23xy;           float vkz  = saz + t23z;
        f2 pnxy = fma2(f2s(dt26), saxy, PB4xy); float pnz = fmaf(dt26, saz, PB4z);
        f2 vpxy = fma2(f2s(dt6), vkxy, vxy); float vpz = fmaf(dt6, vkz, vz);
        float dotppn = dotP(pnxy, pnz);
        float PP1full = b1r6 + dotppn + dotV(vpxy, vpz);
        PP1full = fmaf(dt6, dotV(g4.xy, g4.z), PP1full);

        // ---------------- STAGE 4 ----------------
        mlpchain(pre4, s0, s1, s2);
        float preS1n = fmaf(wc61, s1, fmaf(wc60, s0, fmaf(wc62, s2, PP1full)));
        preS1 = preS1n;
        f2 a4xy = fma2(f2s(scale), (f2){s0, s1}, g4.xy);
        float a4z = fmaf(scale, s2, g4.z);
        f2 vnxy = fma2(f2s(dt6), a4xy, vpxy); float vnz = fmaf(dt6, a4z, vpz);
        G3 g1n = gravity(pnxy, pnz);
        gsb1xy = g1n.xy; gsb1z = g1n.z;
        PB2xy = fma2(f2s(hd),  vnxy, pnxy); PB2z = fmaf(hd,  vnz, pnz);
        PB4xy = fma2(f2s(dtf), vnxy, pnxy); PB4z = fmaf(dtf, vnz, pnz);
        float dotpv2 = dotP(vnxy, vnz);
        float dotvv2 = dotV(vnxy, vnz);
        float base0n = b1r + dotppn + dotvv2;
        PP2raw = fmaf(hd,  dotpv2, base0n + CH);
        PP4raw = fmaf(dtf, dotpv2, base0n + CD);
        PP2full = fmaf(hd, dotV(gsb1xy, gsb1z), PP2raw);
        vxy = vnxy; vz = vnz;

        if (tid == 0) {
            float2* op = (float2*)(out + (size_t)m * 6);
            op[0] = make_float2(pnxy.x, pnxy.y);
            op[1] = make_float2(pnz, vnxy.x);
            op[2] = make_float2(vnxy.y, vnz);
        }
    }
}

extern "C" void kernel_launch(void* const* d_in, const int* in_sizes, int n_in,
                              void* d_out, int out_size, void* d_ws, size_t ws_size,
                              hipStream_t stream) {
    const float* state0 = (const float*)d_in[0];
    // d_in[1] = eval_times (only its length matters)
    const float* W1 = (const float*)d_in[2];
    const float* b1 = (const float*)d_in[3];
    const float* W2 = (const float*)d_in[4];
    const float* b2 = (const float*)d_in[5];
    const float* W3 = (const float*)d_in[6];
    const float* b3 = (const float*)d_in[7];
    const float* ls = (const float*)d_in[8];
    // d_in[9] = t0 (unused)
    const int* pdt  = (const int*)d_in[10];
    const int M = in_sizes[1];

    node_kernel<<<dim3(1), dim3(64), 0, stream>>>(
        state0, W1, b1, W2, b2, W3, b3, ls, pdt, (float*)d_out, M);
}